// Round 1
// baseline (444.966 us; speedup 1.0000x reference)
//
#include <hip/hip_runtime.h>
#include <hip/hip_fp16.h>

// Problem constants (from reference): B=2, CIN=32, COUT=64, K=9, H=256, W=512, OH=256, OW=512
#define HW_IN   131072   // H*W
#define W_IN    512
#define H_IN    256
#define HW_OUT  131072   // OH*OW
#define CIN     32
#define COUT    64
#define KK      9
#define BB      2

typedef _Float16 hf2 __attribute__((ext_vector_type(2)));
typedef _Float16 hf8 __attribute__((ext_vector_type(8)));

static __device__ __forceinline__ hf2 u2h(unsigned int u) {
  return __builtin_bit_cast(hf2, u);
}

#if __has_builtin(__builtin_amdgcn_fdot2)
static __device__ __forceinline__ float fdot2f(hf2 a, hf2 b, float c) {
  return __builtin_amdgcn_fdot2(a, b, c, false);
}
#else
static __device__ __forceinline__ float fdot2f(hf2 a, hf2 b, float c) {
  return c + (float)a[0] * (float)b[0] + (float)a[1] * (float)b[1];
}
#endif

// ---------------------------------------------------------------------------
// Kernel 1: transpose x (B,CIN,H*W) fp32  ->  xt (H*W, B, CIN) f16
// One thread per (b, half, hw); reads coalesced (consecutive hw), writes two
// 16B chunks. Total ~7us-class; correctness-first.
// ---------------------------------------------------------------------------
__global__ __launch_bounds__(256) void transpose_f16(
    const float* __restrict__ x, _Float16* __restrict__ xt) {
  int tid  = blockIdx.x * 256 + threadIdx.x;   // [0, 524288)
  int hw   = tid & (HW_IN - 1);
  int r    = tid >> 17;                        // [0, 4)
  int half = r & 1;
  int b    = r >> 1;

  _Float16 vals[16];
#pragma unroll
  for (int i = 0; i < 16; ++i) {
    int c = half * 16 + i;
    vals[i] = (_Float16)x[(size_t)(b * CIN + c) * HW_IN + hw];
  }
  hf8 v0, v1;
#pragma unroll
  for (int i = 0; i < 8; ++i) { v0[i] = vals[i]; v1[i] = vals[i + 8]; }
  // element offset: hw*64 + b*32 + half*16  (multiple of 16 halfs -> 16B aligned)
  hf8* dst = (hf8*)(xt + (size_t)hw * (BB * CIN) + b * CIN + half * 16);
  dst[0] = v0;
  dst[1] = v1;
}

// ---------------------------------------------------------------------------
// Kernel 2: fused gather + contraction.
// Lane mapping: gtid = ((b*131072 + hw)*4 + q); 4 consecutive lanes (q=0..3)
// share one (b,hw) pixel and split the 32 channels into quarters of 8 so each
// bilinear corner is ONE 64B line fetched by a coalesced 4-lane group.
// Each lane: acc[64] (all couts, partial over its 8 channels), contraction via
// v_dot2_f32_f16 against LDS-resident f16 weight pairs. Then a 2-round
// reduce-scatter across the 4-lane group; each lane stores 16 couts.
// ---------------------------------------------------------------------------
__global__ __launch_bounds__(256, 4) void mapped_conv(
    const _Float16* __restrict__ xt,
    const float* __restrict__ weight,   // [COUT][CIN][KK] fp32
    const float* __restrict__ bias,     // [COUT]
    const float* __restrict__ sm,       // [HW_OUT][KK][2] fp32 (x,y)
    float* __restrict__ out) {          // [BB][COUT][HW_OUT] fp32
  // w_lds layout: [k][c2][o] as half2 over channel pairs (2*c2, 2*c2+1).
  // Row = 64 half2 = 256B; read as uint4 (ds_read_b128).
  __shared__ __align__(16) hf2 w_lds[KK * (CIN / 2) * COUT];  // 9216 * 4B = 36KB
  __shared__ float bias_lds[COUT];

  int t = threadIdx.x;

  // Stage weights: coalesced global read, scattered LDS write (one-time).
  {
    _Float16* wh = (_Float16*)w_lds;
    for (int j = t; j < COUT * CIN * KK; j += 256) {
      unsigned ju = (unsigned)j;
      unsigned o  = ju / 288u;
      unsigned rr = ju % 288u;
      unsigned c  = rr / 9u;
      unsigned k  = rr % 9u;
      wh[((k * 16u + (c >> 1)) * 64u + o) * 2u + (c & 1u)] = (_Float16)weight[j];
    }
    if (t < COUT) bias_lds[t] = bias[t];
  }
  __syncthreads();

  int gtid = blockIdx.x * 256 + t;     // [0, 1048576)
  int q    = gtid & 3;                 // channel quarter
  int pix  = gtid >> 2;                // [0, 262144)
  int hw   = pix & (HW_OUT - 1);
  int b    = pix >> 17;

  const uint4* xt4 = (const uint4*)xt;
  int bq8 = b * 4 + q;                 // uint4-granule offset within a pixel's 64 halfs

  float acc[COUT];
#pragma unroll
  for (int o = 0; o < COUT; ++o) acc[o] = 0.f;

  const float* smp = sm + (size_t)hw * (KK * 2);

#pragma unroll 1
  for (int k = 0; k < KK; ++k) {
    float sx = smp[k * 2 + 0];
    float sy = smp[k * 2 + 1];
    float bx = floorf(sx), by = floorf(sy);
    float fx = sx - bx, fy = sy - by;
    int ix0 = (int)bx, iy0 = (int)by;
    int ix1 = min(ix0 + 1, W_IN - 1);
    int iy1 = min(iy0 + 1, H_IN - 1);
    ix0 = max(min(ix0, W_IN - 1), 0); ix1 = max(ix1, 0);
    iy0 = max(min(iy0, H_IN - 1), 0); iy1 = max(iy1, 0);

    // Each corner: this lane's 8 channels = 16B; 4-lane group = one 64B line.
    uint4 v00 = xt4[(iy0 * W_IN + ix0) * 8 + bq8];
    uint4 v01 = xt4[(iy0 * W_IN + ix1) * 8 + bq8];
    uint4 v10 = xt4[(iy1 * W_IN + ix0) * 8 + bq8];
    uint4 v11 = xt4[(iy1 * W_IN + ix1) * 8 + bq8];

    float w00f = (1.f - fx) * (1.f - fy);
    float w01f = fx * (1.f - fy);
    float w10f = (1.f - fx) * fy;
    float w11f = fx * fy;
    _Float16 h00s = (_Float16)w00f, h01s = (_Float16)w01f;
    _Float16 h10s = (_Float16)w10f, h11s = (_Float16)w11f;
    hf2 h00 = {h00s, h00s}, h01 = {h01s, h01s};
    hf2 h10 = {h10s, h10s}, h11 = {h11s, h11s};

    // Bilinear combine in packed f16: s[cl] = channels (q*8+2cl, q*8+2cl+1)
    hf2 s[4];
    s[0] = h00 * u2h(v00.x) + h01 * u2h(v01.x) + h10 * u2h(v10.x) + h11 * u2h(v11.x);
    s[1] = h00 * u2h(v00.y) + h01 * u2h(v01.y) + h10 * u2h(v10.y) + h11 * u2h(v11.y);
    s[2] = h00 * u2h(v00.z) + h01 * u2h(v01.z) + h10 * u2h(v10.z) + h11 * u2h(v11.z);
    s[3] = h00 * u2h(v00.w) + h01 * u2h(v01.w) + h10 * u2h(v10.w) + h11 * u2h(v11.w);

    // Contraction: row c2 = q*4 + cl; 16x ds_read_b128 + 64x dot2 per cl.
    const uint4* wbase = (const uint4*)w_lds + (size_t)(k * 16 + q * 4) * 16;
#pragma unroll
    for (int cl = 0; cl < 4; ++cl) {
      hf2 s2 = s[cl];
      const uint4* wrow = wbase + cl * 16;
#pragma unroll
      for (int o4 = 0; o4 < 16; ++o4) {
        uint4 wv = wrow[o4];
        acc[o4 * 4 + 0] = fdot2f(u2h(wv.x), s2, acc[o4 * 4 + 0]);
        acc[o4 * 4 + 1] = fdot2f(u2h(wv.y), s2, acc[o4 * 4 + 1]);
        acc[o4 * 4 + 2] = fdot2f(u2h(wv.z), s2, acc[o4 * 4 + 2]);
        acc[o4 * 4 + 3] = fdot2f(u2h(wv.w), s2, acc[o4 * 4 + 3]);
      }
    }
  }

  // Reduce-scatter across the 4-lane group (masks 1 then 2). All register
  // indices are static; selection is by value (v_cndmask), no scratch.
  float r1[32];
#pragma unroll
  for (int j = 0; j < 32; ++j) {
    bool up = (q & 1);
    float keep = up ? acc[j + 32] : acc[j];
    float send = up ? acc[j] : acc[j + 32];
    r1[j] = keep + __shfl_xor(send, 1, 64);
  }
  float r2[16];
#pragma unroll
  for (int j = 0; j < 16; ++j) {
    bool up = (q & 2);
    float keep = up ? r1[j + 16] : r1[j];
    float send = up ? r1[j] : r1[j + 16];
    r2[j] = keep + __shfl_xor(send, 2, 64);
  }
  // Lane q now holds couts [o_base, o_base+16): o_base in {0,32,16,48}
  int o_base = (q & 1) * 32 + (q & 2) * 8;

  float* outp = out + (size_t)(b * COUT + o_base) * HW_OUT + hw;
#pragma unroll
  for (int i = 0; i < 16; ++i) {
    outp[(size_t)i * HW_OUT] = r2[i] + bias_lds[o_base + i];
  }
}

extern "C" void kernel_launch(void* const* d_in, const int* in_sizes, int n_in,
                              void* d_out, int out_size, void* d_ws, size_t ws_size,
                              hipStream_t stream) {
  const float* x  = (const float*)d_in[0];   // [B][CIN][H*W]
  const float* w  = (const float*)d_in[1];   // [COUT][CIN][KK]
  const float* bs = (const float*)d_in[2];   // [COUT]
  const float* sm = (const float*)d_in[3];   // [OH*OW][KK][2]
  float* out = (float*)d_out;                // [B][COUT][OH*OW]
  _Float16* xt = (_Float16*)d_ws;            // 16 MB scratch: (H*W, B, CIN) f16

  transpose_f16<<<dim3(2048), dim3(256), 0, stream>>>(x, xt);
  mapped_conv<<<dim3(4096), dim3(256), 0, stream>>>(xt, w, bs, sm, out);
}

// Round 2
// 252.340 us; speedup vs baseline: 1.7634x; 1.7634x over previous
//
#include <hip/hip_runtime.h>
#include <hip/hip_fp16.h>

// Problem constants: B=2, CIN=32, COUT=64, K=9, H=256, W=512, OH=256, OW=512
#define HW_IN   131072
#define W_IN    512
#define H_IN    256
#define HW_OUT  131072
#define CIN     32
#define COUT    64
#define KK      9
#define BB      2

typedef _Float16 hf2 __attribute__((ext_vector_type(2)));
typedef _Float16 hf8 __attribute__((ext_vector_type(8)));
typedef float f32x4 __attribute__((ext_vector_type(4)));

static __device__ __forceinline__ hf8 u4h(uint4 u) {
  return __builtin_bit_cast(hf8, u);
}

// ---------------------------------------------------------------------------
// Kernel 1: transpose x (B,CIN,H*W) fp32 -> xt (H*W, B, CIN) f16.
// One pixel's 64 channels (b-major) = one 128B pair of lines; a bilinear
// corner for one (b, quarter) = 16B, one 64B line per 4-lane set.
// ---------------------------------------------------------------------------
__global__ __launch_bounds__(256) void transpose_f16(
    const float* __restrict__ x, _Float16* __restrict__ xt) {
  int tid  = blockIdx.x * 256 + threadIdx.x;   // [0, 524288)
  int hw   = tid & (HW_IN - 1);
  int r    = tid >> 17;                        // [0, 4)
  int half = r & 1;
  int b    = r >> 1;

  _Float16 vals[16];
#pragma unroll
  for (int i = 0; i < 16; ++i) {
    int c = half * 16 + i;
    vals[i] = (_Float16)x[(size_t)(b * CIN + c) * HW_IN + hw];
  }
  hf8 v0, v1;
#pragma unroll
  for (int i = 0; i < 8; ++i) { v0[i] = vals[i]; v1[i] = vals[i + 8]; }
  hf8* dst = (hf8*)(xt + (size_t)hw * (BB * CIN) + b * CIN + half * 16);
  dst[0] = v0;
  dst[1] = v1;
}

// ---------------------------------------------------------------------------
// Kernel 2: fused gather + MFMA contraction.
// GEMM view: out[pix, o] = sum_{ck=k*32+c} samp[pix, ck] * W[o, ck].
// One wave = 16 pixels (M-tile) x 64 couts (4 N-tiles), K=288 as 9 taps x 32.
// A-frag (16x16x32 f16): lane m=lane&15 -> pixel, quad=lane>>4 -> channel
// quarter; lane holds 8 bilinear-sampled halves = its quarter's channels.
// Gather: corner line = 64B; lanes {m, m+16, m+32, m+48} fetch its 4 quarters.
// B-frag: lane n=lane&15 -> cout, quad*8+j -> channel. LDS layout
// [k][o][c] halves: per (k, N-tile) a contiguous 1024B region read disjointly
// by 64 lanes -> zero bank conflicts.
// C/D: col(lane&15)=cout, row(quad*4+reg)=pixel -> float4 store of 4
// consecutive hw per lane, fully coalesced.
// ---------------------------------------------------------------------------
__global__ __launch_bounds__(256, 4) void mapped_conv_mfma(
    const _Float16* __restrict__ xt,
    const float* __restrict__ weight,   // [COUT][CIN][KK] fp32
    const float* __restrict__ bias,     // [COUT]
    const float* __restrict__ sm,       // [HW_OUT][KK][2] fp32
    float* __restrict__ out) {          // [BB][COUT][HW_OUT] fp32
  __shared__ __align__(16) _Float16 w_lds[KK * COUT * CIN];  // 36 KB

  int t = threadIdx.x;
  // Stage weights: w_lds[(k*64 + o)*32 + c] = W[o][c][k] as f16.
  for (int j = t; j < COUT * CIN * KK; j += 256) {
    unsigned ju = (unsigned)j;
    unsigned o  = ju / 288u;
    unsigned rr = ju % 288u;
    unsigned c  = rr / 9u;
    unsigned k  = rr % 9u;
    w_lds[(k * 64u + o) * 32u + c] = (_Float16)weight[ju];
  }
  __syncthreads();

  int wave = t >> 6;
  int lane = t & 63;
  int m    = lane & 15;   // A-row: pixel within tile; also B-col: cout within N-tile
  int quad = lane >> 4;   // channel quarter (A) / k-quarter (B) / row group (C)

  int pix_base = blockIdx.x * 64 + wave * 16;     // 4096 blocks x 4 waves
  int pix  = pix_base + m;
  int b    = pix_base >> 17;                      // wave-uniform
  int hw   = pix & (HW_OUT - 1);
  int hw_base = pix_base & (HW_OUT - 1);

  const uint4* xt4 = (const uint4*)xt;
  int bq = b * 4 + quad;   // uint4-granule within a pixel's 64 halves

  f32x4 acc[4] = {{0.f,0.f,0.f,0.f},{0.f,0.f,0.f,0.f},
                  {0.f,0.f,0.f,0.f},{0.f,0.f,0.f,0.f}};

  const float* smp = sm + (size_t)hw * (KK * 2);
  // B-frag base granule for this lane: (k*64 + nt*16 + m)*4 + quad
  const uint4* wbl = (const uint4*)w_lds + (size_t)(m * 4 + quad);

#pragma unroll 3
  for (int k = 0; k < KK; ++k) {
    float sx = smp[k * 2 + 0];
    float sy = smp[k * 2 + 1];
    float bxf = floorf(sx), byf = floorf(sy);
    float fx = sx - bxf, fy = sy - byf;
    int ix0 = (int)bxf, iy0 = (int)byf;
    int ix1 = min(ix0 + 1, W_IN - 1);
    int iy1 = min(iy0 + 1, H_IN - 1);
    ix0 = max(min(ix0, W_IN - 1), 0); ix1 = max(ix1, 0);
    iy0 = max(min(iy0, H_IN - 1), 0); iy1 = max(iy1, 0);

    uint4 v00 = xt4[(iy0 * W_IN + ix0) * 8 + bq];
    uint4 v01 = xt4[(iy0 * W_IN + ix1) * 8 + bq];
    uint4 v10 = xt4[(iy1 * W_IN + ix0) * 8 + bq];
    uint4 v11 = xt4[(iy1 * W_IN + ix1) * 8 + bq];

    _Float16 w00 = (_Float16)((1.f - fx) * (1.f - fy));
    _Float16 w01 = (_Float16)(fx * (1.f - fy));
    _Float16 w10 = (_Float16)((1.f - fx) * fy);
    _Float16 w11 = (_Float16)(fx * fy);
    hf8 h00 = {w00, w00, w00, w00, w00, w00, w00, w00};
    hf8 h01 = {w01, w01, w01, w01, w01, w01, w01, w01};
    hf8 h10 = {w10, w10, w10, w10, w10, w10, w10, w10};
    hf8 h11 = {w11, w11, w11, w11, w11, w11, w11, w11};

    hf8 a = h00 * u4h(v00) + h01 * u4h(v01) + h10 * u4h(v10) + h11 * u4h(v11);

    const uint4* wk = wbl + (size_t)k * 256;   // per-k block = 64 o * 4 granules
    hf8 b0 = u4h(wk[0]);     // N-tile 0: o in [0,16)
    hf8 b1 = u4h(wk[64]);    // N-tile 1
    hf8 b2 = u4h(wk[128]);   // N-tile 2
    hf8 b3 = u4h(wk[192]);   // N-tile 3

    acc[0] = __builtin_amdgcn_mfma_f32_16x16x32_f16(a, b0, acc[0], 0, 0, 0);
    acc[1] = __builtin_amdgcn_mfma_f32_16x16x32_f16(a, b1, acc[1], 0, 0, 0);
    acc[2] = __builtin_amdgcn_mfma_f32_16x16x32_f16(a, b2, acc[2], 0, 0, 0);
    acc[3] = __builtin_amdgcn_mfma_f32_16x16x32_f16(a, b3, acc[3], 0, 0, 0);
  }

  // Epilogue: lane writes 4 consecutive pixels (rows quad*4..+3) for cout n.
  int hw0 = hw_base + quad * 4;
#pragma unroll
  for (int nt = 0; nt < 4; ++nt) {
    int n = nt * 16 + m;
    float bn = bias[n];
    float4 v = make_float4(acc[nt][0] + bn, acc[nt][1] + bn,
                           acc[nt][2] + bn, acc[nt][3] + bn);
    float* op = out + (size_t)(b * COUT + n) * HW_OUT + hw0;
    *(float4*)op = v;
  }
}

extern "C" void kernel_launch(void* const* d_in, const int* in_sizes, int n_in,
                              void* d_out, int out_size, void* d_ws, size_t ws_size,
                              hipStream_t stream) {
  const float* x  = (const float*)d_in[0];   // [B][CIN][H*W]
  const float* w  = (const float*)d_in[1];   // [COUT][CIN][KK]
  const float* bs = (const float*)d_in[2];   // [COUT]
  const float* sm = (const float*)d_in[3];   // [OH*OW][KK][2]
  float* out = (float*)d_out;                // [B][COUT][OH*OW]
  _Float16* xt = (_Float16*)d_ws;            // 16 MB scratch: (H*W, B, CIN) f16

  transpose_f16<<<dim3(2048), dim3(256), 0, stream>>>(x, xt);
  mapped_conv_mfma<<<dim3(4096), dim3(256), 0, stream>>>(xt, w, bs, sm, out);
}